// Round 4
// baseline (547.740 us; speedup 1.0000x reference)
//
#include <hip/hip_runtime.h>
#include <math.h>

#define N_NODES 100000
#define HDIM    128
#define ODIM    40
#define NBLK    ((N_NODES + 255) / 256)   // 391

typedef unsigned short u16;
typedef unsigned int   u32;
typedef short bf16x8 __attribute__((ext_vector_type(8)));   // 8 bf16 in 4 VGPRs
typedef float f32x4  __attribute__((ext_vector_type(4)));

// ---------------- bf16 helpers ----------------
__device__ inline float bf16lo_to_f(u32 v) {
    u32 u = v << 16; float f; __builtin_memcpy(&f, &u, 4); return f;
}
__device__ inline float bf16hi_to_f(u32 v) {
    u32 u = v & 0xffff0000u; float f; __builtin_memcpy(&f, &u, 4); return f;
}
__device__ inline u16 f_to_bf16(float f) {
    u32 u; __builtin_memcpy(&u, &f, 4);
    u32 r = (u + 0x7fffu + ((u >> 16) & 1u)) >> 16;   // round-nearest-even
    return (u16)r;
}
__device__ inline u32 pack_bf16x2(float a, float b) {
    return (u32)f_to_bf16(a) | ((u32)f_to_bf16(b) << 16);
}

// ---------------------------------------------------------------------------
// CSR build (counting sort by dst).
// ---------------------------------------------------------------------------
__global__ __launch_bounds__(256) void count_deg_kernel(
    const int* __restrict__ dst, int* __restrict__ ic, int E)
{
    int e = blockIdx.x * 256 + threadIdx.x;
    if (e < E) atomicAdd(ic + dst[e], 1);
}

__global__ __launch_bounds__(256) void block_sum_kernel(
    const int* __restrict__ ic, int* __restrict__ bs, int n)
{
    __shared__ int sm[256];
    int t = threadIdx.x;
    int i = blockIdx.x * 256 + t;
    sm[t] = (i < n) ? ic[i] : 0;
    __syncthreads();
    for (int s = 128; s > 0; s >>= 1) {
        if (t < s) sm[t] += sm[t + s];
        __syncthreads();
    }
    if (t == 0) bs[blockIdx.x] = sm[0];
}

__global__ __launch_bounds__(512) void scan_bs_kernel(int* __restrict__ bs, int nb)
{
    __shared__ int sm[512];
    int t = threadIdx.x;
    sm[t] = (t < nb) ? bs[t] : 0;
    __syncthreads();
    for (int off = 1; off < 512; off <<= 1) {
        int v = (t >= off) ? sm[t - off] : 0;
        __syncthreads();
        sm[t] += v;
        __syncthreads();
    }
    if (t < nb) bs[t] = (t == 0) ? 0 : sm[t - 1];
}

__global__ __launch_bounds__(256) void scan_block_kernel(
    const int* __restrict__ ic, const int* __restrict__ bs,
    int* __restrict__ pc, int n)
{
    __shared__ int sm[256];
    int t = threadIdx.x;
    int i = blockIdx.x * 256 + t;
    int v = (i < n) ? ic[i] : 0;
    sm[t] = v;
    __syncthreads();
    for (int off = 1; off < 256; off <<= 1) {
        int u = (t >= off) ? sm[t - off] : 0;
        __syncthreads();
        sm[t] += u;
        __syncthreads();
    }
    if (i < n) pc[i] = bs[blockIdx.x] + sm[t] - v;   // exclusive
}

__global__ __launch_bounds__(256) void fill_kernel(
    const int* __restrict__ src, const int* __restrict__ dst,
    int* __restrict__ pc, int* __restrict__ cs, int E)
{
    int e = blockIdx.x * 256 + threadIdx.x;
    if (e < E) {
        int p = atomicAdd(pc + dst[e], 1);
        cs[p] = src[e];
    }
}
// after fill: end(n) = pc[n], start(n) = pc[n] - ic[n]

// ---------------------------------------------------------------------------
// fp32 -> bf16 feature conversion (2 elements / thread).
// ---------------------------------------------------------------------------
__global__ __launch_bounds__(256) void f2bf_kernel(
    const float2* __restrict__ in, u32* __restrict__ out, int n2)
{
    int i = blockIdx.x * 256 + threadIdx.x;
    if (i < n2) { float2 v = in[i]; out[i] = pack_bf16x2(v.x, v.y); }
}

// ---------------------------------------------------------------------------
// Pack 128x128 fp32 weight matrices into bf16 MFMA B-fragment order:
//   frag (ntile, kslice): 64 lanes x 8 bf16, lane = q*16 + (n&15),
//   element j: B[k = kslice*32 + q*8 + j][n = ntile*16 + (n&15)]
// ---------------------------------------------------------------------------
struct WPtrs { const float* w[7]; };

__global__ __launch_bounds__(256) void pack_w_kernel(WPtrs p, u16* __restrict__ out)
{
    int mat = blockIdx.y;
    int e = blockIdx.x * 256 + threadIdx.x;      // 0..16383
    int k = e >> 7, n = e & 127;
    float v = p.w[mat][e];
    int nt = n >> 4, ks = k >> 5, q = (k >> 3) & 3, j = k & 7;
    int dst = mat * 16384 + (((nt * 4 + ks) * 64 + q * 16 + (n & 15)) << 3) + j;
    out[dst] = f_to_bf16(v);
}

// Pack Wf2 [128][40] into 128x48 (zero-padded) B-frag order: 3 ntiles x 4 ks.
__global__ __launch_bounds__(256) void pack_wf2_kernel(
    const float* __restrict__ Wf2, u16* __restrict__ outp)
{
    int e = blockIdx.x * 256 + threadIdx.x;      // 0..6143 (128*48)
    if (e >= 128 * 48) return;
    int k = e / 48, n = e - k * 48;
    float v = (n < ODIM) ? Wf2[k * ODIM + n] : 0.f;
    int nt = n >> 4, ks = k >> 5, q = (k >> 3) & 3, j = k & 7;
    outp[(((nt * 4 + ks) * 64 + q * 16 + (n & 15)) << 3) + j] = f_to_bf16(v);
}

// ---------------------------------------------------------------------------
// In-block gather phase: 16 groups x 16 lanes; group g computes the mean
// rows of nodes base+b*16+g (b=0..7) and writes bf16 results into the
// block's LDS tile sBuf[128][136]. Same arithmetic/rounding as the old
// standalone gather (depth-2 pipelined neighbor loads).
// ---------------------------------------------------------------------------
__device__ inline void gather_phase(
    const u32* __restrict__ feat32, const int* __restrict__ cs,
    const int* __restrict__ pc, const int* __restrict__ ic,
    u16* __restrict__ sBuf, int base, int tid)
{
    const int grp = tid >> 4;
    const int ch  = tid & 15;
    const u32* fb = feat32 + (ch << 2);
    const uint4 Z = {0u, 0u, 0u, 0u};

    for (int b = 0; b < 8; ++b) {
        int rl = b * 16 + grp;
        int node = base + rl;
        int deg = 0, start = 0;
        if (node < N_NODES) { int e = pc[node]; deg = ic[node]; start = e - deg; }

        float acc[8] = {0.f,0.f,0.f,0.f,0.f,0.f,0.f,0.f};
        if (deg > 0) {
            uint4 c0 = *reinterpret_cast<const uint4*>(fb + ((size_t)cs[start] << 6));
            uint4 c1 = (deg > 1)
                ? *reinterpret_cast<const uint4*>(fb + ((size_t)cs[start + 1] << 6)) : Z;
            for (int j = 0; j < deg; ++j) {
                uint4 nx = (j + 2 < deg)
                    ? *reinterpret_cast<const uint4*>(fb + ((size_t)cs[start + j + 2] << 6)) : Z;
                acc[0] += bf16lo_to_f(c0.x); acc[1] += bf16hi_to_f(c0.x);
                acc[2] += bf16lo_to_f(c0.y); acc[3] += bf16hi_to_f(c0.y);
                acc[4] += bf16lo_to_f(c0.z); acc[5] += bf16hi_to_f(c0.z);
                acc[6] += bf16lo_to_f(c0.w); acc[7] += bf16hi_to_f(c0.w);
                c0 = c1; c1 = nx;
            }
        }
        float inv = 1.0f / (float)(deg > 0 ? deg : 1);
        uint4 o;
        o.x = pack_bf16x2(acc[0] * inv, acc[1] * inv);
        o.y = pack_bf16x2(acc[2] * inv, acc[3] * inv);
        o.z = pack_bf16x2(acc[4] * inv, acc[5] * inv);
        o.w = pack_bf16x2(acc[6] * inv, acc[7] * inv);
        *reinterpret_cast<uint4*>(sBuf + rl * 136 + (ch << 3)) = o;
    }
}

// Stage a packed W matrix (nchunk4*4 KB) linearly into LDS via global_load_lds.
__device__ inline void stage_w(const u16* __restrict__ Wp, u16* __restrict__ sDst,
                               int wave, int lane, int nchunk4)
{
    for (int it = 0; it < nchunk4; ++it) {
        int off = (it * 4 + wave) << 9;             // 1 KB chunks
        __builtin_amdgcn_global_load_lds(
            (const __attribute__((address_space(1))) void*)(Wp + off + (lane << 3)),
            (__attribute__((address_space(3))) void*)(sDst + off), 16, 0, 0);
    }
}

// Row-wise log_softmax over 40 cols for one 64-row tile held as 3 f32x4
// accumulators per lane; quad-local (16-lane) shuffle reductions.
__device__ inline void head_softmax_store(
    const f32x4* acc2, const float* __restrict__ bf2, float* __restrict__ out,
    int rowbase, int m, int q)
{
    float z[3][4];
    float mx[4] = {-INFINITY, -INFINITY, -INFINITY, -INFINITY};
    #pragma unroll
    for (int nt = 0; nt < 3; ++nt) {
        int col = nt * 16 + m;
        bool valid = (col < ODIM);
        float bv = valid ? bf2[col] : 0.f;
        #pragma unroll
        for (int r = 0; r < 4; ++r) {
            z[nt][r] = acc2[nt][r] + bv;
            if (valid) mx[r] = fmaxf(mx[r], z[nt][r]);
        }
    }
    #pragma unroll
    for (int off = 1; off < 16; off <<= 1) {
        #pragma unroll
        for (int r = 0; r < 4; ++r) mx[r] = fmaxf(mx[r], __shfl_xor(mx[r], off, 16));
    }
    float sum[4] = {0.f, 0.f, 0.f, 0.f};
    #pragma unroll
    for (int nt = 0; nt < 3; ++nt) {
        int col = nt * 16 + m;
        if (col < ODIM) {
            #pragma unroll
            for (int r = 0; r < 4; ++r) sum[r] += expf(z[nt][r] - mx[r]);
        }
    }
    #pragma unroll
    for (int off = 1; off < 16; off <<= 1) {
        #pragma unroll
        for (int r = 0; r < 4; ++r) sum[r] += __shfl_xor(sum[r], off, 16);
    }
    float lse[4];
    #pragma unroll
    for (int r = 0; r < 4; ++r) lse[r] = logf(sum[r]) + mx[r];

    #pragma unroll
    for (int nt = 0; nt < 3; ++nt) {
        int col = nt * 16 + m;
        if (col >= ODIM) continue;
        #pragma unroll
        for (int r = 0; r < 4; ++r) {
            int rowg = rowbase + q * 4 + r;
            if (rowg < N_NODES) out[(size_t)rowg * ODIM + col] = z[nt][r] - lse[r];
        }
    }
}

// ---------------------------------------------------------------------------
// Fused SAGE layer: gather(mean) -> LDS -> dual MFMA GEMM -> relu -> bf16 out.
// 128 rows/block. The gathered A-matrix never touches global memory.
// ---------------------------------------------------------------------------
__global__ __launch_bounds__(256) void sage_layer_kernel(
    const u16* __restrict__ feat,    // [N][128] bf16 input features
    const int* __restrict__ cs, const int* __restrict__ pc, const int* __restrict__ ic,
    const u16* __restrict__ Wlp, const u16* __restrict__ Wrp,
    const float* __restrict__ bias,
    u16* __restrict__ out16)
{
    __shared__ __align__(16) u16 sBuf[128 * 136];   // 34.8 KB: A-tile / W frags / out stage
    const int tid  = threadIdx.x;
    const int wave = tid >> 6;
    const int lane = tid & 63;
    const int m = lane & 15;
    const int q = lane >> 4;
    const int base = blockIdx.x * 128;

    // ---- phase G: gathered means -> sBuf[row][136] ----
    gather_phase((const u32*)feat, cs, pc, ic, sBuf, base, tid);
    __syncthreads();

    // ---- gathered a-frags LDS -> regs ----
    const int rl0 = wave * 16 + m;
    const int rl1 = rl0 + 64;
    bf16x8 g0[4], g1[4];
    #pragma unroll
    for (int ks = 0; ks < 4; ++ks) {
        g0[ks] = *reinterpret_cast<const bf16x8*>(sBuf + rl0 * 136 + ((ks * 4 + q) << 3));
        g1[ks] = *reinterpret_cast<const bf16x8*>(sBuf + rl1 * 136 + ((ks * 4 + q) << 3));
    }
    __syncthreads();   // A-tile dead; sBuf reusable for W

    // ---- self-feature a-frags direct from global (contiguous rows) ----
    int row0 = base + rl0; if (row0 > N_NODES - 1) row0 = N_NODES - 1;
    int row1 = base + rl1; if (row1 > N_NODES - 1) row1 = N_NODES - 1;
    bf16x8 s0[4], s1[4];
    #pragma unroll
    for (int ks = 0; ks < 4; ++ks) {
        s0[ks] = *reinterpret_cast<const bf16x8*>(feat + ((size_t)row0 << 7) + ((ks * 4 + q) << 3));
        s1[ks] = *reinterpret_cast<const bf16x8*>(feat + ((size_t)row1 << 7) + ((ks * 4 + q) << 3));
    }

    f32x4 acc0[8], acc1[8];
    #pragma unroll
    for (int nt = 0; nt < 8; ++nt) {
        acc0[nt] = (f32x4){0.f, 0.f, 0.f, 0.f};
        acc1[nt] = (f32x4){0.f, 0.f, 0.f, 0.f};
    }

    // ---- mat 1: aggr @ Wl ----
    stage_w(Wlp, sBuf, wave, lane, 8);
    __syncthreads();
    #pragma unroll
    for (int ks = 0; ks < 4; ++ks) {
        #pragma unroll
        for (int nt = 0; nt < 8; ++nt) {
            bf16x8 b = *reinterpret_cast<const bf16x8*>(sBuf + (((nt * 4 + ks) * 64 + lane) << 3));
            acc0[nt] = __builtin_amdgcn_mfma_f32_16x16x32_bf16(g0[ks], b, acc0[nt], 0, 0, 0);
            acc1[nt] = __builtin_amdgcn_mfma_f32_16x16x32_bf16(g1[ks], b, acc1[nt], 0, 0, 0);
        }
    }
    __syncthreads();

    // ---- mat 2: self @ Wr ----
    stage_w(Wrp, sBuf, wave, lane, 8);
    __syncthreads();
    #pragma unroll
    for (int ks = 0; ks < 4; ++ks) {
        #pragma unroll
        for (int nt = 0; nt < 8; ++nt) {
            bf16x8 b = *reinterpret_cast<const bf16x8*>(sBuf + (((nt * 4 + ks) * 64 + lane) << 3));
            acc0[nt] = __builtin_amdgcn_mfma_f32_16x16x32_bf16(s0[ks], b, acc0[nt], 0, 0, 0);
            acc1[nt] = __builtin_amdgcn_mfma_f32_16x16x32_bf16(s1[ks], b, acc1[nt], 0, 0, 0);
        }
    }
    __syncthreads();   // W frags dead

    // ---- epilogue: bias + relu, LDS stage, coalesced uint4 out ----
    #pragma unroll
    for (int nt = 0; nt < 8; ++nt) {
        int col = nt * 16 + m;
        float bv = bias[col];
        #pragma unroll
        for (int r = 0; r < 4; ++r) {
            float v0 = fmaxf(acc0[nt][r] + bv, 0.f);
            float v1 = fmaxf(acc1[nt][r] + bv, 0.f);
            int rlr = wave * 16 + q * 4 + r;
            sBuf[rlr * 136 + col] = f_to_bf16(v0);
            sBuf[(rlr + 64) * 136 + col] = f_to_bf16(v1);
        }
    }
    __syncthreads();

    #pragma unroll
    for (int it = 0; it < 8; ++it) {
        int c = it * 256 + tid;
        int row = c >> 4, ch = c & 15;
        int rowg = base + row;
        if (rowg < N_NODES)
            *reinterpret_cast<uint4*>(out16 + ((size_t)rowg << 7) + (ch << 3)) =
                *reinterpret_cast<const uint4*>(sBuf + row * 136 + (ch << 3));
    }
}

// ---------------------------------------------------------------------------
// Fused layer 3 + MLP head: gather -> dual GEMM (h3, fp32 out) -> Wf1 GEMM
// -> relu -> Wf2 GEMM -> log_softmax, all in one block. h3's bf16 copy and
// t never touch global memory.
// ---------------------------------------------------------------------------
__global__ __launch_bounds__(256) void sage_l3_head_kernel(
    const u16* __restrict__ feat,    // [N][128] bf16 (h2)
    const int* __restrict__ cs, const int* __restrict__ pc, const int* __restrict__ ic,
    const u16* __restrict__ W3lp, const u16* __restrict__ W3rp,
    const float* __restrict__ b3,
    const u16* __restrict__ Wf1p, const float* __restrict__ bf1,
    const u16* __restrict__ Wf2p, const float* __restrict__ bf2,
    float* __restrict__ hout,        // [N][128] fp32 h3
    float* __restrict__ out)         // [N][40] log_softmax
{
    __shared__ __align__(16) u16 sBuf[128 * 136];
    const int tid  = threadIdx.x;
    const int wave = tid >> 6;
    const int lane = tid & 63;
    const int m = lane & 15;
    const int q = lane >> 4;
    const int base = blockIdx.x * 128;

    // ---- phase G ----
    gather_phase((const u32*)feat, cs, pc, ic, sBuf, base, tid);
    __syncthreads();

    const int rl0 = wave * 16 + m;
    const int rl1 = rl0 + 64;
    bf16x8 g0[4], g1[4];
    #pragma unroll
    for (int ks = 0; ks < 4; ++ks) {
        g0[ks] = *reinterpret_cast<const bf16x8*>(sBuf + rl0 * 136 + ((ks * 4 + q) << 3));
        g1[ks] = *reinterpret_cast<const bf16x8*>(sBuf + rl1 * 136 + ((ks * 4 + q) << 3));
    }
    __syncthreads();

    int row0 = base + rl0; if (row0 > N_NODES - 1) row0 = N_NODES - 1;
    int row1 = base + rl1; if (row1 > N_NODES - 1) row1 = N_NODES - 1;
    bf16x8 s0[4], s1[4];
    #pragma unroll
    for (int ks = 0; ks < 4; ++ks) {
        s0[ks] = *reinterpret_cast<const bf16x8*>(feat + ((size_t)row0 << 7) + ((ks * 4 + q) << 3));
        s1[ks] = *reinterpret_cast<const bf16x8*>(feat + ((size_t)row1 << 7) + ((ks * 4 + q) << 3));
    }

    f32x4 acc0[8], acc1[8];
    #pragma unroll
    for (int nt = 0; nt < 8; ++nt) {
        acc0[nt] = (f32x4){0.f, 0.f, 0.f, 0.f};
        acc1[nt] = (f32x4){0.f, 0.f, 0.f, 0.f};
    }

    stage_w(W3lp, sBuf, wave, lane, 8);
    __syncthreads();
    #pragma unroll
    for (int ks = 0; ks < 4; ++ks) {
        #pragma unroll
        for (int nt = 0; nt < 8; ++nt) {
            bf16x8 b = *reinterpret_cast<const bf16x8*>(sBuf + (((nt * 4 + ks) * 64 + lane) << 3));
            acc0[nt] = __builtin_amdgcn_mfma_f32_16x16x32_bf16(g0[ks], b, acc0[nt], 0, 0, 0);
            acc1[nt] = __builtin_amdgcn_mfma_f32_16x16x32_bf16(g1[ks], b, acc1[nt], 0, 0, 0);
        }
    }
    __syncthreads();
    stage_w(W3rp, sBuf, wave, lane, 8);
    __syncthreads();
    #pragma unroll
    for (int ks = 0; ks < 4; ++ks) {
        #pragma unroll
        for (int nt = 0; nt < 8; ++nt) {
            bf16x8 b = *reinterpret_cast<const bf16x8*>(sBuf + (((nt * 4 + ks) * 64 + lane) << 3));
            acc0[nt] = __builtin_amdgcn_mfma_f32_16x16x32_bf16(s0[ks], b, acc0[nt], 0, 0, 0);
            acc1[nt] = __builtin_amdgcn_mfma_f32_16x16x32_bf16(s1[ks], b, acc1[nt], 0, 0, 0);
        }
    }
    __syncthreads();

    // ---- h3 = acc + b3 (no relu): fp32 direct out + bf16 into LDS ----
    #pragma unroll
    for (int nt = 0; nt < 8; ++nt) {
        int col = nt * 16 + m;
        float bv = b3[col];
        #pragma unroll
        for (int r = 0; r < 4; ++r) {
            float v0 = acc0[nt][r] + bv;
            float v1 = acc1[nt][r] + bv;
            int rlr = wave * 16 + q * 4 + r;
            sBuf[rlr * 136 + col] = f_to_bf16(v0);
            sBuf[(rlr + 64) * 136 + col] = f_to_bf16(v1);
            int rg0 = base + rlr, rg1 = base + rlr + 64;
            if (rg0 < N_NODES) hout[((size_t)rg0 << 7) + col] = v0;
            if (rg1 < N_NODES) hout[((size_t)rg1 << 7) + col] = v1;
        }
    }
    __syncthreads();

    // ---- h-frags from LDS ----
    bf16x8 h0[4], h1[4];
    #pragma unroll
    for (int ks = 0; ks < 4; ++ks) {
        h0[ks] = *reinterpret_cast<const bf16x8*>(sBuf + rl0 * 136 + ((ks * 4 + q) << 3));
        h1[ks] = *reinterpret_cast<const bf16x8*>(sBuf + rl1 * 136 + ((ks * 4 + q) << 3));
    }
    __syncthreads();

    // ---- head GEMM1: h3 @ Wf1 ----
    stage_w(Wf1p, sBuf, wave, lane, 8);
    __syncthreads();
    #pragma unroll
    for (int nt = 0; nt < 8; ++nt) {
        acc0[nt] = (f32x4){0.f, 0.f, 0.f, 0.f};
        acc1[nt] = (f32x4){0.f, 0.f, 0.f, 0.f};
    }
    #pragma unroll
    for (int ks = 0; ks < 4; ++ks) {
        #pragma unroll
        for (int nt = 0; nt < 8; ++nt) {
            bf16x8 b = *reinterpret_cast<const bf16x8*>(sBuf + (((nt * 4 + ks) * 64 + lane) << 3));
            acc0[nt] = __builtin_amdgcn_mfma_f32_16x16x32_bf16(h0[ks], b, acc0[nt], 0, 0, 0);
            acc1[nt] = __builtin_amdgcn_mfma_f32_16x16x32_bf16(h1[ks], b, acc1[nt], 0, 0, 0);
        }
    }
    __syncthreads();

    // ---- t = relu(acc + bf1) -> LDS ----
    #pragma unroll
    for (int nt = 0; nt < 8; ++nt) {
        int col = nt * 16 + m;
        float bv = bf1[col];
        #pragma unroll
        for (int r = 0; r < 4; ++r) {
            int rlr = wave * 16 + q * 4 + r;
            sBuf[rlr * 136 + col] = f_to_bf16(fmaxf(acc0[nt][r] + bv, 0.f));
            sBuf[(rlr + 64) * 136 + col] = f_to_bf16(fmaxf(acc1[nt][r] + bv, 0.f));
        }
    }
    __syncthreads();

    bf16x8 t0[4], t1[4];
    #pragma unroll
    for (int ks = 0; ks < 4; ++ks) {
        t0[ks] = *reinterpret_cast<const bf16x8*>(sBuf + rl0 * 136 + ((ks * 4 + q) << 3));
        t1[ks] = *reinterpret_cast<const bf16x8*>(sBuf + rl1 * 136 + ((ks * 4 + q) << 3));
    }
    __syncthreads();

    // ---- head GEMM2: z = t @ Wf2 (48-padded) ----
    stage_w(Wf2p, sBuf, wave, lane, 3);
    __syncthreads();
    f32x4 ca[3], cb[3];
    #pragma unroll
    for (int nt = 0; nt < 3; ++nt) {
        ca[nt] = (f32x4){0.f, 0.f, 0.f, 0.f};
        cb[nt] = (f32x4){0.f, 0.f, 0.f, 0.f};
    }
    #pragma unroll
    for (int ks = 0; ks < 4; ++ks) {
        #pragma unroll
        for (int nt = 0; nt < 3; ++nt) {
            bf16x8 b = *reinterpret_cast<const bf16x8*>(sBuf + (((nt * 4 + ks) * 64 + lane) << 3));
            ca[nt] = __builtin_amdgcn_mfma_f32_16x16x32_bf16(t0[ks], b, ca[nt], 0, 0, 0);
            cb[nt] = __builtin_amdgcn_mfma_f32_16x16x32_bf16(t1[ks], b, cb[nt], 0, 0, 0);
        }
    }

    // ---- log_softmax per 64-row tile ----
    head_softmax_store(ca, bf2, out, base + wave * 16, m, q);
    head_softmax_store(cb, bf2, out, base + 64 + wave * 16, m, q);
}

// ---------------------------------------------------------------------------
extern "C" void kernel_launch(void* const* d_in, const int* in_sizes, int n_in,
                              void* d_out, int out_size, void* d_ws, size_t ws_size,
                              hipStream_t stream) {
    const float* x   = (const float*)d_in[0];
    const int*   ei  = (const int*)d_in[1];
    const int E = in_sizes[1] / 2;
    const int* src = ei;
    const int* dst = ei + E;

    const float* W1l = (const float*)d_in[2];
    const float* b1  = (const float*)d_in[3];
    const float* W1r = (const float*)d_in[4];
    const float* W2l = (const float*)d_in[5];
    const float* b2  = (const float*)d_in[6];
    const float* W2r = (const float*)d_in[7];
    const float* W3l = (const float*)d_in[8];
    const float* b3  = (const float*)d_in[9];
    const float* W3r = (const float*)d_in[10];
    const float* Wf1 = (const float*)d_in[11];
    const float* bf1 = (const float*)d_in[12];
    const float* Wf2 = (const float*)d_in[13];
    const float* bf2 = (const float*)d_in[14];

    float* out     = (float*)d_out;
    float* outTail = out + (size_t)N_NODES * ODIM;   // tuple part 2: h [N,128] fp32

    // Workspace (u16 units): X16 | F16a | F16b | CSR (in old A16 slot) | Wpk | Wf2p
    // CSR must NOT alias d_out: the fused l3+head kernel reads cs while
    // writing out.
    const size_t FEAT16 = (size_t)N_NODES * HDIM;   // 12.8M u16 = 25.6 MB
    u16* X16  = (u16*)d_ws;
    u16* F16a = X16  + FEAT16;
    u16* F16b = F16a + FEAT16;
    int* ic = (int*)(F16b + FEAT16);                // 100352 ints
    int* pc = ic + 100352;                          // 100352 ints
    int* bs = pc + 100352;                          // 1024 ints
    int* cs = bs + 1024;                            // E ints (total ~3.4 MB < 25.6 MB slot)
    u16* Wpk  = X16 + 4 * FEAT16;                   // 7*16384 u16
    u16* Wp_1l = Wpk + 0 * 16384;
    u16* Wp_1r = Wpk + 1 * 16384;
    u16* Wp_2l = Wpk + 2 * 16384;
    u16* Wp_2r = Wpk + 3 * 16384;
    u16* Wp_3l = Wpk + 4 * 16384;
    u16* Wp_3r = Wpk + 5 * 16384;
    u16* Wp_f1 = Wpk + 6 * 16384;
    u16* Wf2p  = Wpk + 7 * 16384;                   // 6144 u16

    const int layerGrid  = (N_NODES + 127) / 128; // 782
    const int edgeGrid   = (E + 255) / 256;       // 2500
    const int cvtGrid    = (N_NODES * HDIM / 2 + 255) / 256;  // 25000

    // ---- CSR build ----
    hipMemsetAsync(ic, 0, N_NODES * sizeof(int), stream);
    count_deg_kernel<<<edgeGrid, 256, 0, stream>>>(dst, ic, E);
    block_sum_kernel<<<NBLK, 256, 0, stream>>>(ic, bs, N_NODES);
    scan_bs_kernel<<<1, 512, 0, stream>>>(bs, NBLK);
    scan_block_kernel<<<NBLK, 256, 0, stream>>>(ic, bs, pc, N_NODES);
    fill_kernel<<<edgeGrid, 256, 0, stream>>>(src, dst, pc, cs, E);

    // ---- prep: x -> bf16, pack weights ----
    f2bf_kernel<<<cvtGrid, 256, 0, stream>>>((const float2*)x, (u32*)X16, N_NODES * HDIM / 2);
    WPtrs wp; wp.w[0] = W1l; wp.w[1] = W1r; wp.w[2] = W2l; wp.w[3] = W2r;
    wp.w[4] = W3l; wp.w[5] = W3r; wp.w[6] = Wf1;
    pack_w_kernel<<<dim3(64, 7), 256, 0, stream>>>(wp, Wpk);
    pack_wf2_kernel<<<24, 256, 0, stream>>>(Wf2, Wf2p);

    // ---- layer 1: X16 -> F16a (gather fused) ----
    sage_layer_kernel<<<layerGrid, 256, 0, stream>>>(
        X16, cs, pc, ic, Wp_1l, Wp_1r, b1, F16a);

    // ---- layer 2: F16a -> F16b ----
    sage_layer_kernel<<<layerGrid, 256, 0, stream>>>(
        F16a, cs, pc, ic, Wp_2l, Wp_2r, b2, F16b);

    // ---- layer 3 + MLP head + log_softmax ----
    sage_l3_head_kernel<<<layerGrid, 256, 0, stream>>>(
        F16b, cs, pc, ic, Wp_3l, Wp_3r, b3, Wp_f1, bf1, Wf2p, bf2, outTail, out);
}

// Round 5
// 398.743 us; speedup vs baseline: 1.3737x; 1.3737x over previous
//
#include <hip/hip_runtime.h>
#include <math.h>

#define N_NODES 100000
#define HDIM    128
#define ODIM    40
#define NBLK    ((N_NODES + 255) / 256)   // 391

typedef unsigned short u16;
typedef unsigned int   u32;
typedef short bf16x8 __attribute__((ext_vector_type(8)));   // 8 bf16 in 4 VGPRs
typedef float f32x4  __attribute__((ext_vector_type(4)));

// ---------------- bf16 helpers ----------------
__device__ inline float bf16lo_to_f(u32 v) {
    u32 u = v << 16; float f; __builtin_memcpy(&f, &u, 4); return f;
}
__device__ inline float bf16hi_to_f(u32 v) {
    u32 u = v & 0xffff0000u; float f; __builtin_memcpy(&f, &u, 4); return f;
}
__device__ inline u16 f_to_bf16(float f) {
    u32 u; __builtin_memcpy(&u, &f, 4);
    u32 r = (u + 0x7fffu + ((u >> 16) & 1u)) >> 16;   // round-nearest-even
    return (u16)r;
}
__device__ inline u32 pack_bf16x2(float a, float b) {
    return (u32)f_to_bf16(a) | ((u32)f_to_bf16(b) << 16);
}

// ---------------------------------------------------------------------------
// CSR build (counting sort by dst).
// ---------------------------------------------------------------------------
__global__ __launch_bounds__(256) void count_deg_kernel(
    const int* __restrict__ dst, int* __restrict__ ic, int E)
{
    int e = blockIdx.x * 256 + threadIdx.x;
    if (e < E) atomicAdd(ic + dst[e], 1);
}

__global__ __launch_bounds__(256) void block_sum_kernel(
    const int* __restrict__ ic, int* __restrict__ bs, int n)
{
    __shared__ int sm[256];
    int t = threadIdx.x;
    int i = blockIdx.x * 256 + t;
    sm[t] = (i < n) ? ic[i] : 0;
    __syncthreads();
    for (int s = 128; s > 0; s >>= 1) {
        if (t < s) sm[t] += sm[t + s];
        __syncthreads();
    }
    if (t == 0) bs[blockIdx.x] = sm[0];
}

__global__ __launch_bounds__(512) void scan_bs_kernel(int* __restrict__ bs, int nb)
{
    __shared__ int sm[512];
    int t = threadIdx.x;
    sm[t] = (t < nb) ? bs[t] : 0;
    __syncthreads();
    for (int off = 1; off < 512; off <<= 1) {
        int v = (t >= off) ? sm[t - off] : 0;
        __syncthreads();
        sm[t] += v;
        __syncthreads();
    }
    if (t < nb) bs[t] = (t == 0) ? 0 : sm[t - 1];
}

__global__ __launch_bounds__(256) void scan_block_kernel(
    const int* __restrict__ ic, const int* __restrict__ bs,
    int* __restrict__ pc, int n)
{
    __shared__ int sm[256];
    int t = threadIdx.x;
    int i = blockIdx.x * 256 + t;
    int v = (i < n) ? ic[i] : 0;
    sm[t] = v;
    __syncthreads();
    for (int off = 1; off < 256; off <<= 1) {
        int u = (t >= off) ? sm[t - off] : 0;
        __syncthreads();
        sm[t] += u;
        __syncthreads();
    }
    if (i < n) pc[i] = bs[blockIdx.x] + sm[t] - v;   // exclusive
}

__global__ __launch_bounds__(256) void fill_kernel(
    const int* __restrict__ src, const int* __restrict__ dst,
    int* __restrict__ pc, int* __restrict__ cs, int E)
{
    int e = blockIdx.x * 256 + threadIdx.x;
    if (e < E) {
        int p = atomicAdd(pc + dst[e], 1);
        cs[p] = src[e];
    }
}
// after fill: end(n) = pc[n], start(n) = pc[n] - ic[n]

// ---------------------------------------------------------------------------
// Fused prologue: one dispatch doing (by blockIdx.x range)
//   [0, 25000)      : fp32 -> bf16 feature conversion (2 el/thread)
//   [25000, 25448)  : pack 7 128x128 W mats into B-frag order (mat = blk>>6)
//   [25448, 25472)  : pack Wf2 [128][40] into 128x48-padded B-frag order
//   [25472, 25864)  : zero ic (degree counters)
// All pieces are independent and precede their consumers.
// ---------------------------------------------------------------------------
struct WPtrs { const float* w[7]; };

#define PREP_F2BF  25000
#define PREP_PACKW (PREP_F2BF + 448)
#define PREP_WF2   (PREP_PACKW + 24)
#define PREP_ZERO  (PREP_WF2 + 392)

__global__ __launch_bounds__(256) void prep_kernel(
    const float2* __restrict__ x2, u32* __restrict__ X32,
    WPtrs p, u16* __restrict__ Wpk,
    const float* __restrict__ Wf2, u16* __restrict__ Wf2p,
    int* __restrict__ ic)
{
    const int b = blockIdx.x;
    const int tid = threadIdx.x;
    if (b < PREP_F2BF) {
        int i = b * 256 + tid;                    // n2 = 6,400,000 = 25000*256 exact
        float2 v = x2[i];
        X32[i] = pack_bf16x2(v.x, v.y);
    } else if (b < PREP_PACKW) {
        int bb = b - PREP_F2BF;
        int mat = bb >> 6;
        int e = (bb & 63) * 256 + tid;            // 0..16383
        int k = e >> 7, n = e & 127;
        float v = p.w[mat][e];
        int nt = n >> 4, ks = k >> 5, q = (k >> 3) & 3, j = k & 7;
        Wpk[mat * 16384 + (((nt * 4 + ks) * 64 + q * 16 + (n & 15)) << 3) + j] = f_to_bf16(v);
    } else if (b < PREP_WF2) {
        int e = (b - PREP_PACKW) * 256 + tid;     // 0..6143 (128*48)
        if (e < 128 * 48) {
            int k = e / 48, n = e - k * 48;
            float v = (n < ODIM) ? Wf2[k * ODIM + n] : 0.f;
            int nt = n >> 4, ks = k >> 5, q = (k >> 3) & 3, j = k & 7;
            Wf2p[(((nt * 4 + ks) * 64 + q * 16 + (n & 15)) << 3) + j] = f_to_bf16(v);
        }
    } else {
        int i = (b - PREP_WF2) * 256 + tid;       // 392*256 = 100352
        if (i < 100352) ic[i] = 0;
    }
}

// ---------------------------------------------------------------------------
// Mean-gather, one 16-lane group per node (16 nodes/block, 4/wave).
// Measured memory-system-bound (~41 us); byte-identical to round 3.
// ---------------------------------------------------------------------------
__global__ __launch_bounds__(256) void gather_mean_grp_kernel(
    const u32* __restrict__ feat,    // [N][64] u32 (=128 bf16)
    const int* __restrict__ cs, const int* __restrict__ pc, const int* __restrict__ ic,
    u32* __restrict__ A)             // [N][64] u32
{
    const int grp  = threadIdx.x >> 4;            // 0..15
    const int ch   = threadIdx.x & 15;            // 16B chunk within row
    const int node = blockIdx.x * 16 + grp;       // grid*16 == N exactly
    const int end  = pc[node];
    const int deg  = ic[node];
    const int start = end - deg;

    const u32* fb = feat + (ch << 2);             // lane's chunk base

    float acc[8] = {0.f,0.f,0.f,0.f,0.f,0.f,0.f,0.f};
    const uint4 Z = {0u, 0u, 0u, 0u};

    if (deg > 0) {
        uint4 c0 = *reinterpret_cast<const uint4*>(fb + ((size_t)cs[start] << 6));
        uint4 c1 = (deg > 1)
            ? *reinterpret_cast<const uint4*>(fb + ((size_t)cs[start + 1] << 6)) : Z;
        for (int j = 0; j < deg; ++j) {
            uint4 n = (j + 2 < deg)
                ? *reinterpret_cast<const uint4*>(fb + ((size_t)cs[start + j + 2] << 6)) : Z;
            acc[0] += bf16lo_to_f(c0.x); acc[1] += bf16hi_to_f(c0.x);
            acc[2] += bf16lo_to_f(c0.y); acc[3] += bf16hi_to_f(c0.y);
            acc[4] += bf16lo_to_f(c0.z); acc[5] += bf16hi_to_f(c0.z);
            acc[6] += bf16lo_to_f(c0.w); acc[7] += bf16hi_to_f(c0.w);
            c0 = c1; c1 = n;
        }
    }

    float inv = 1.0f / (float)(deg > 0 ? deg : 1);
    uint4 o;
    o.x = pack_bf16x2(acc[0] * inv, acc[1] * inv);
    o.y = pack_bf16x2(acc[2] * inv, acc[3] * inv);
    o.z = pack_bf16x2(acc[4] * inv, acc[5] * inv);
    o.w = pack_bf16x2(acc[6] * inv, acc[7] * inv);
    *reinterpret_cast<uint4*>(A + ((size_t)node << 6) + (ch << 2)) = o;
}

// Stage a packed W matrix (nchunk4*4 KB) linearly into LDS via global_load_lds.
__device__ inline void stage_w(const u16* __restrict__ Wp, u16* __restrict__ sDst,
                               int wave, int lane, int nchunk4)
{
    for (int it = 0; it < nchunk4; ++it) {
        int off = (it * 4 + wave) << 9;             // 1 KB chunks
        __builtin_amdgcn_global_load_lds(
            (const __attribute__((address_space(1))) void*)(Wp + off + (lane << 3)),
            (__attribute__((address_space(3))) void*)(sDst + off), 16, 0, 0);
    }
}

// ---------------------------------------------------------------------------
// MFMA dual GEMM (round-3 proven): out = [relu]( A1 @ W1 + bias [+ A2 @ W2] )
// W staged to LDS per block; a-frags direct to registers; 128 rows/block;
// bf16 out staged via LDS for coalesced uint4 stores; fp32 out direct.
// ---------------------------------------------------------------------------
__global__ __launch_bounds__(256) void mfma_gemm_kernel(
    const u16* __restrict__ A1, const u16* __restrict__ A2,
    const u16* __restrict__ W1p, const u16* __restrict__ W2p,
    const float* __restrict__ bias,
    u16* __restrict__ out16, float* __restrict__ out32, int do_relu)
{
    __shared__ __align__(16) u16 sBuf[128 * 136];   // 34.8 KB: W frags, then out staging
    const int tid  = threadIdx.x;
    const int wave = tid >> 6;
    const int lane = tid & 63;
    const int m = lane & 15;
    const int q = lane >> 4;
    const int base = blockIdx.x * 128;

    int row0 = base + wave * 16 + m;        if (row0 > N_NODES - 1) row0 = N_NODES - 1;
    int row1 = base + (wave + 4) * 16 + m;  if (row1 > N_NODES - 1) row1 = N_NODES - 1;

    f32x4 acc0[8], acc1[8];
    #pragma unroll
    for (int nt = 0; nt < 8; ++nt) {
        acc0[nt] = (f32x4){0.f, 0.f, 0.f, 0.f};
        acc1[nt] = (f32x4){0.f, 0.f, 0.f, 0.f};
    }

    // ---- mat 0: prefetch a-frags to regs, stage W1 to LDS ----
    bf16x8 a0[4], a1[4];
    #pragma unroll
    for (int ks = 0; ks < 4; ++ks) {
        a0[ks] = *reinterpret_cast<const bf16x8*>(A1 + ((size_t)row0 << 7) + ((ks * 4 + q) << 3));
        a1[ks] = *reinterpret_cast<const bf16x8*>(A1 + ((size_t)row1 << 7) + ((ks * 4 + q) << 3));
    }
    stage_w(W1p, sBuf, wave, lane, 8);
    __syncthreads();

    #pragma unroll
    for (int ks = 0; ks < 4; ++ks) {
        #pragma unroll
        for (int nt = 0; nt < 8; ++nt) {
            bf16x8 b = *reinterpret_cast<const bf16x8*>(sBuf + (((nt * 4 + ks) * 64 + lane) << 3));
            acc0[nt] = __builtin_amdgcn_mfma_f32_16x16x32_bf16(a0[ks], b, acc0[nt], 0, 0, 0);
            acc1[nt] = __builtin_amdgcn_mfma_f32_16x16x32_bf16(a1[ks], b, acc1[nt], 0, 0, 0);
        }
    }

    if (A2 != nullptr) {
        __syncthreads();   // all waves done reading W1 frags
        #pragma unroll
        for (int ks = 0; ks < 4; ++ks) {
            a0[ks] = *reinterpret_cast<const bf16x8*>(A2 + ((size_t)row0 << 7) + ((ks * 4 + q) << 3));
            a1[ks] = *reinterpret_cast<const bf16x8*>(A2 + ((size_t)row1 << 7) + ((ks * 4 + q) << 3));
        }
        stage_w(W2p, sBuf, wave, lane, 8);
        __syncthreads();

        #pragma unroll
        for (int ks = 0; ks < 4; ++ks) {
            #pragma unroll
            for (int nt = 0; nt < 8; ++nt) {
                bf16x8 b = *reinterpret_cast<const bf16x8*>(sBuf + (((nt * 4 + ks) * 64 + lane) << 3));
                acc0[nt] = __builtin_amdgcn_mfma_f32_16x16x32_bf16(a0[ks], b, acc0[nt], 0, 0, 0);
                acc1[nt] = __builtin_amdgcn_mfma_f32_16x16x32_bf16(a1[ks], b, acc1[nt], 0, 0, 0);
            }
        }
    }
    __syncthreads();   // W frags dead; sBuf reusable for out staging

    // ---- epilogue ----
    #pragma unroll
    for (int nt = 0; nt < 8; ++nt) {
        int col = nt * 16 + m;
        float bv = bias[col];
        #pragma unroll
        for (int r = 0; r < 4; ++r) {
            float v0 = acc0[nt][r] + bv;
            float v1 = acc1[nt][r] + bv;
            if (do_relu) { v0 = fmaxf(v0, 0.f); v1 = fmaxf(v1, 0.f); }
            int rl0 = wave * 16 + q * 4 + r;
            int rl1 = rl0 + 64;
            sBuf[rl0 * 136 + col] = f_to_bf16(v0);
            sBuf[rl1 * 136 + col] = f_to_bf16(v1);
            if (out32) {
                int rg0 = base + rl0, rg1 = base + rl1;
                if (rg0 < N_NODES) out32[((size_t)rg0 << 7) + col] = v0;
                if (rg1 < N_NODES) out32[((size_t)rg1 << 7) + col] = v1;
            }
        }
    }
    __syncthreads();

    if (out16) {
        #pragma unroll
        for (int it = 0; it < 8; ++it) {
            int c = it * 256 + tid;
            int row = c >> 4, ch = c & 15;
            int rowg = base + row;
            if (rowg < N_NODES)
                *reinterpret_cast<uint4*>(out16 + ((size_t)rowg << 7) + (ch << 3)) =
                    *reinterpret_cast<const uint4*>(sBuf + row * 136 + (ch << 3));
        }
    }
}

// ---------------------------------------------------------------------------
// Fused MLP head, 128 rows/block: t = relu(h3 @ Wf1 + bf1) kept on-chip
// (two 64-row A-frag tiles written into the dead Wf1 LDS buffer), then
// z = t @ Wf2 + bf2 and row-wise log_softmax in registers. Wf1 and Wf2 are
// both staged up-front (separate buffers); W-stage traffic halved vs 64-row.
// ---------------------------------------------------------------------------
__global__ __launch_bounds__(256) void mfma_head_kernel(
    const u16* __restrict__ h3,      // bf16 [N][128]
    const u16* __restrict__ Wf1p, const float* __restrict__ bf1,
    const u16* __restrict__ Wf2p, const float* __restrict__ bf2,
    float* __restrict__ out)         // [N][40]
{
    __shared__ __align__(16) u16 sW1[16384];   // 32 KB: Wf1 frags -> t (2x64-row tiles)
    __shared__ __align__(16) u16 sW2[6144];    // 12 KB: Wf2 frags
    const int tid  = threadIdx.x;
    const int wave = tid >> 6;
    const int lane = tid & 63;
    const int m = lane & 15;
    const int q = lane >> 4;
    const int base = blockIdx.x * 128;

    int row0 = base + wave * 16 + m;       if (row0 > N_NODES - 1) row0 = N_NODES - 1;
    int row1 = base + 64 + wave * 16 + m;  if (row1 > N_NODES - 1) row1 = N_NODES - 1;

    bf16x8 a0[4], a1[4];
    #pragma unroll
    for (int ks = 0; ks < 4; ++ks) {
        a0[ks] = *reinterpret_cast<const bf16x8*>(h3 + ((size_t)row0 << 7) + ((ks * 4 + q) << 3));
        a1[ks] = *reinterpret_cast<const bf16x8*>(h3 + ((size_t)row1 << 7) + ((ks * 4 + q) << 3));
    }
    stage_w(Wf1p, sW1, wave, lane, 8);
    stage_w(Wf2p, sW2, wave, lane, 3);
    __syncthreads();

    // ---- GEMM1: acc = h3 @ Wf1 ----
    f32x4 acc0[8], acc1[8];
    #pragma unroll
    for (int nt = 0; nt < 8; ++nt) {
        acc0[nt] = (f32x4){0.f, 0.f, 0.f, 0.f};
        acc1[nt] = (f32x4){0.f, 0.f, 0.f, 0.f};
    }
    #pragma unroll
    for (int ks = 0; ks < 4; ++ks) {
        #pragma unroll
        for (int nt = 0; nt < 8; ++nt) {
            bf16x8 b = *reinterpret_cast<const bf16x8*>(sW1 + (((nt * 4 + ks) * 64 + lane) << 3));
            acc0[nt] = __builtin_amdgcn_mfma_f32_16x16x32_bf16(a0[ks], b, acc0[nt], 0, 0, 0);
            acc1[nt] = __builtin_amdgcn_mfma_f32_16x16x32_bf16(a1[ks], b, acc1[nt], 0, 0, 0);
        }
    }
    __syncthreads();   // Wf1 frags consumed; reuse sW1 for t

    // ---- t = relu(acc + bf1) -> sW1 (A-frag order; tile0 @0, tile1 @8192) ----
    #pragma unroll
    for (int nt = 0; nt < 8; ++nt) {
        int col = nt * 16 + m;
        float bv = bf1[col];
        #pragma unroll
        for (int r = 0; r < 4; ++r) {
            int dc = (wave * 4 + (nt >> 1)) * 64 + ((nt & 1) * 2 + (m >> 3)) * 16 + (q * 4 + r);
            sW1[(dc << 3) | (m & 7)]        = f_to_bf16(fmaxf(acc0[nt][r] + bv, 0.f));
            sW1[8192 + ((dc << 3) | (m & 7))] = f_to_bf16(fmaxf(acc1[nt][r] + bv, 0.f));
        }
    }
    __syncthreads();

    // ---- GEMM2: z = t @ Wf2 (48-padded cols) ----
    f32x4 ca[3], cb[3];
    #pragma unroll
    for (int nt = 0; nt < 3; ++nt) {
        ca[nt] = (f32x4){0.f, 0.f, 0.f, 0.f};
        cb[nt] = (f32x4){0.f, 0.f, 0.f, 0.f};
    }
    #pragma unroll
    for (int ks = 0; ks < 4; ++ks) {
        bf16x8 t0 = *reinterpret_cast<const bf16x8*>(sW1 + (((wave * 4 + ks) * 64 + lane) << 3));
        bf16x8 t1 = *reinterpret_cast<const bf16x8*>(sW1 + 8192 + (((wave * 4 + ks) * 64 + lane) << 3));
        #pragma unroll
        for (int nt = 0; nt < 3; ++nt) {
            bf16x8 b = *reinterpret_cast<const bf16x8*>(sW2 + (((nt * 4 + ks) * 64 + lane) << 3));
            ca[nt] = __builtin_amdgcn_mfma_f32_16x16x32_bf16(t0, b, ca[nt], 0, 0, 0);
            cb[nt] = __builtin_amdgcn_mfma_f32_16x16x32_bf16(t1, b, cb[nt], 0, 0, 0);
        }
    }

    // ---- log_softmax per 64-row tile, quad-local shuffle reductions ----
    #pragma unroll
    for (int tile = 0; tile < 2; ++tile) {
        const f32x4* acc2 = tile ? cb : ca;
        float z[3][4];
        float mx[4] = {-INFINITY, -INFINITY, -INFINITY, -INFINITY};
        #pragma unroll
        for (int nt = 0; nt < 3; ++nt) {
            int col = nt * 16 + m;
            bool valid = (col < ODIM);
            float bv = valid ? bf2[col] : 0.f;
            #pragma unroll
            for (int r = 0; r < 4; ++r) {
                z[nt][r] = acc2[nt][r] + bv;
                if (valid) mx[r] = fmaxf(mx[r], z[nt][r]);
            }
        }
        #pragma unroll
        for (int off = 1; off < 16; off <<= 1) {
            #pragma unroll
            for (int r = 0; r < 4; ++r) mx[r] = fmaxf(mx[r], __shfl_xor(mx[r], off, 16));
        }
        float sum[4] = {0.f, 0.f, 0.f, 0.f};
        #pragma unroll
        for (int nt = 0; nt < 3; ++nt) {
            int col = nt * 16 + m;
            if (col < ODIM) {
                #pragma unroll
                for (int r = 0; r < 4; ++r) sum[r] += expf(z[nt][r] - mx[r]);
            }
        }
        #pragma unroll
        for (int off = 1; off < 16; off <<= 1) {
            #pragma unroll
            for (int r = 0; r < 4; ++r) sum[r] += __shfl_xor(sum[r], off, 16);
        }
        float lse[4];
        #pragma unroll
        for (int r = 0; r < 4; ++r) lse[r] = logf(sum[r]) + mx[r];

        int rowbase = base + tile * 64 + wave * 16;
        #pragma unroll
        for (int nt = 0; nt < 3; ++nt) {
            int col = nt * 16 + m;
            if (col >= ODIM) continue;
            #pragma unroll
            for (int r = 0; r < 4; ++r) {
                int rowg = rowbase + q * 4 + r;
                if (rowg < N_NODES) out[(size_t)rowg * ODIM + col] = z[nt][r] - lse[r];
            }
        }
    }
}

// ---------------------------------------------------------------------------
extern "C" void kernel_launch(void* const* d_in, const int* in_sizes, int n_in,
                              void* d_out, int out_size, void* d_ws, size_t ws_size,
                              hipStream_t stream) {
    const float* x   = (const float*)d_in[0];
    const int*   ei  = (const int*)d_in[1];
    const int E = in_sizes[1] / 2;
    const int* src = ei;
    const int* dst = ei + E;

    const float* W1l = (const float*)d_in[2];
    const float* b1  = (const float*)d_in[3];
    const float* W1r = (const float*)d_in[4];
    const float* W2l = (const float*)d_in[5];
    const float* b2  = (const float*)d_in[6];
    const float* W2r = (const float*)d_in[7];
    const float* W3l = (const float*)d_in[8];
    const float* b3  = (const float*)d_in[9];
    const float* W3r = (const float*)d_in[10];
    const float* Wf1 = (const float*)d_in[11];
    const float* bf1 = (const float*)d_in[12];
    const float* Wf2 = (const float*)d_in[13];
    const float* bf2 = (const float*)d_in[14];

    float* out     = (float*)d_out;
    float* outTail = out + (size_t)N_NODES * ODIM;   // tuple part 2: h [N,128] fp32

    // CSR arrays live in d_out HEAD (overwritten by final softmax, which
    // launches after the last CSR use — head kernel reads no CSR).
    int* ic = (int*)out;            // 100352 ints
    int* pc = ic + 100352;          // 100352 ints
    int* bs = pc + 100352;          // 1024 ints
    int* cs = bs + 1024;            // E ints  (total ~3.4 MB < 16 MB head)

    // Workspace (u16 units): X16 | F16a | F16b | A16 | Wpk(7x16384) | Wf2p
    const size_t FEAT16 = (size_t)N_NODES * HDIM;   // 12.8M u16 = 25.6 MB
    u16* X16  = (u16*)d_ws;
    u16* F16a = X16  + FEAT16;
    u16* F16b = F16a + FEAT16;
    u16* A16  = F16b + FEAT16;
    u16* Wpk  = A16  + FEAT16;                      // 7*16384 u16
    u16* Wp_1l = Wpk + 0 * 16384;
    u16* Wp_1r = Wpk + 1 * 16384;
    u16* Wp_2l = Wpk + 2 * 16384;
    u16* Wp_2r = Wpk + 3 * 16384;
    u16* Wp_3l = Wpk + 4 * 16384;
    u16* Wp_3r = Wpk + 5 * 16384;
    u16* Wp_f1 = Wpk + 6 * 16384;
    u16* Wf2p  = Wpk + 7 * 16384;                   // 6144 u16

    const int gemmGrid   = (N_NODES + 127) / 128; // 782
    const int gatherGrid = N_NODES / 16;          // 6250 (16 nodes/block, exact)
    const int edgeGrid   = (E + 255) / 256;       // 2500

    // ---- fused prologue: f2bf + weight packs + ic zero (1 dispatch) ----
    WPtrs wp; wp.w[0] = W1l; wp.w[1] = W1r; wp.w[2] = W2l; wp.w[3] = W2r;
    wp.w[4] = W3l; wp.w[5] = W3r; wp.w[6] = Wf1;
    prep_kernel<<<PREP_ZERO, 256, 0, stream>>>(
        (const float2*)x, (u32*)X16, wp, Wpk, Wf2, Wf2p, ic);

    // ---- CSR build ----
    count_deg_kernel<<<edgeGrid, 256, 0, stream>>>(dst, ic, E);
    block_sum_kernel<<<NBLK, 256, 0, stream>>>(ic, bs, N_NODES);
    scan_bs_kernel<<<1, 512, 0, stream>>>(bs, NBLK);
    scan_block_kernel<<<NBLK, 256, 0, stream>>>(ic, bs, pc, N_NODES);
    fill_kernel<<<edgeGrid, 256, 0, stream>>>(src, dst, pc, cs, E);

    // ---- layer 1: X16 -> F16a ----
    gather_mean_grp_kernel<<<gatherGrid, 256, 0, stream>>>((const u32*)X16, cs, pc, ic, (u32*)A16);
    mfma_gemm_kernel<<<gemmGrid, 256, 0, stream>>>(A16, X16, Wp_1l, Wp_1r, b1, F16a, nullptr, 1);

    // ---- layer 2: F16a -> F16b ----
    gather_mean_grp_kernel<<<gatherGrid, 256, 0, stream>>>((const u32*)F16a, cs, pc, ic, (u32*)A16);
    mfma_gemm_kernel<<<gemmGrid, 256, 0, stream>>>(A16, F16a, Wp_2l, Wp_2r, b2, F16b, nullptr, 1);

    // ---- layer 3: F16b -> F16a (bf16) + outTail (fp32 h3), no relu ----
    gather_mean_grp_kernel<<<gatherGrid, 256, 0, stream>>>((const u32*)F16b, cs, pc, ic, (u32*)A16);
    mfma_gemm_kernel<<<gemmGrid, 256, 0, stream>>>(A16, F16b, Wp_3l, Wp_3r, b3, F16a, outTail, 0);

    // ---- fused MLP head + log_softmax -> out head (overwrites CSR debris) ----
    mfma_head_kernel<<<gemmGrid, 256, 0, stream>>>(F16a, Wp_f1, bf1, Wf2p, bf2, out);
}

// Round 7
// 389.379 us; speedup vs baseline: 1.4067x; 1.0240x over previous
//
#include <hip/hip_runtime.h>
#include <math.h>

#define N_NODES 100000
#define HDIM    128
#define ODIM    40
#define NBLK    ((N_NODES + 255) / 256)   // 391

typedef unsigned short u16;
typedef unsigned int   u32;
typedef short bf16x8 __attribute__((ext_vector_type(8)));   // 8 bf16 in 4 VGPRs
typedef float f32x4  __attribute__((ext_vector_type(4)));

// ---------------- bf16 helpers ----------------
__device__ inline float bf16lo_to_f(u32 v) {
    u32 u = v << 16; float f; __builtin_memcpy(&f, &u, 4); return f;
}
__device__ inline float bf16hi_to_f(u32 v) {
    u32 u = v & 0xffff0000u; float f; __builtin_memcpy(&f, &u, 4); return f;
}
__device__ inline u16 f_to_bf16(float f) {
    u32 u; __builtin_memcpy(&u, &f, 4);
    u32 r = (u + 0x7fffu + ((u >> 16) & 1u)) >> 16;   // round-nearest-even
    return (u16)r;
}
__device__ inline u32 pack_bf16x2(float a, float b) {
    return (u32)f_to_bf16(a) | ((u32)f_to_bf16(b) << 16);
}

// ---------------------------------------------------------------------------
// CSR build (counting sort by dst).
// ---------------------------------------------------------------------------
__global__ __launch_bounds__(256) void count_deg_kernel(
    const int* __restrict__ dst, int* __restrict__ ic, int E)
{
    int e = blockIdx.x * 256 + threadIdx.x;
    if (e < E) atomicAdd(ic + dst[e], 1);
}

__global__ __launch_bounds__(256) void block_sum_kernel(
    const int* __restrict__ ic, int* __restrict__ bs, int n)
{
    __shared__ int sm[256];
    int t = threadIdx.x;
    int i = blockIdx.x * 256 + t;
    sm[t] = (i < n) ? ic[i] : 0;
    __syncthreads();
    for (int s = 128; s > 0; s >>= 1) {
        if (t < s) sm[t] += sm[t + s];
        __syncthreads();
    }
    if (t == 0) bs[blockIdx.x] = sm[0];
}

__global__ __launch_bounds__(512) void scan_bs_kernel(int* __restrict__ bs, int nb)
{
    __shared__ int sm[512];
    int t = threadIdx.x;
    sm[t] = (t < nb) ? bs[t] : 0;
    __syncthreads();
    for (int off = 1; off < 512; off <<= 1) {
        int v = (t >= off) ? sm[t - off] : 0;
        __syncthreads();
        sm[t] += v;
        __syncthreads();
    }
    if (t < nb) bs[t] = (t == 0) ? 0 : sm[t - 1];
}

__global__ __launch_bounds__(256) void scan_block_kernel(
    const int* __restrict__ ic, const int* __restrict__ bs,
    int* __restrict__ pc, int n)
{
    __shared__ int sm[256];
    int t = threadIdx.x;
    int i = blockIdx.x * 256 + t;
    int v = (i < n) ? ic[i] : 0;
    sm[t] = v;
    __syncthreads();
    for (int off = 1; off < 256; off <<= 1) {
        int u = (t >= off) ? sm[t - off] : 0;
        __syncthreads();
        sm[t] += u;
        __syncthreads();
    }
    if (i < n) pc[i] = bs[blockIdx.x] + sm[t] - v;   // exclusive
}

__global__ __launch_bounds__(256) void fill_kernel(
    const int* __restrict__ src, const int* __restrict__ dst,
    int* __restrict__ pc, int* __restrict__ cs, int E)
{
    int e = blockIdx.x * 256 + threadIdx.x;
    if (e < E) {
        int p = atomicAdd(pc + dst[e], 1);
        cs[p] = src[e];
    }
}
// after fill: end(n) = pc[n], start(n) = pc[n] - ic[n]

// ---------------------------------------------------------------------------
// Fused prologue: one dispatch doing (by blockIdx.x range)
//   [0, 25000)      : fp32 -> bf16 feature conversion (2 el/thread)
//   [25000, 25448)  : pack 7 128x128 W mats into B-frag order (mat = blk>>6)
//   [25448, 25472)  : pack Wf2 [128][40] into 128x48-padded B-frag order
//   [25472, 25864)  : zero ic (degree counters)
// ---------------------------------------------------------------------------
struct WPtrs { const float* w[7]; };

#define PREP_F2BF  25000
#define PREP_PACKW (PREP_F2BF + 448)
#define PREP_WF2   (PREP_PACKW + 24)
#define PREP_ZERO  (PREP_WF2 + 392)

__global__ __launch_bounds__(256) void prep_kernel(
    const float2* __restrict__ x2, u32* __restrict__ X32,
    WPtrs p, u16* __restrict__ Wpk,
    const float* __restrict__ Wf2, u16* __restrict__ Wf2p,
    int* __restrict__ ic)
{
    const int b = blockIdx.x;
    const int tid = threadIdx.x;
    if (b < PREP_F2BF) {
        int i = b * 256 + tid;                    // n2 = 6,400,000 = 25000*256 exact
        float2 v = x2[i];
        X32[i] = pack_bf16x2(v.x, v.y);
    } else if (b < PREP_PACKW) {
        int bb = b - PREP_F2BF;
        int mat = bb >> 6;
        int e = (bb & 63) * 256 + tid;            // 0..16383
        int k = e >> 7, n = e & 127;
        float v = p.w[mat][e];
        int nt = n >> 4, ks = k >> 5, q = (k >> 3) & 3, j = k & 7;
        Wpk[mat * 16384 + (((nt * 4 + ks) * 64 + q * 16 + (n & 15)) << 3) + j] = f_to_bf16(v);
    } else if (b < PREP_WF2) {
        int e = (b - PREP_PACKW) * 256 + tid;     // 0..6143 (128*48)
        if (e < 128 * 48) {
            int k = e / 48, n = e - k * 48;
            float v = (n < ODIM) ? Wf2[k * ODIM + n] : 0.f;
            int nt = n >> 4, ks = k >> 5, q = (k >> 3) & 3, j = k & 7;
            Wf2p[(((nt * 4 + ks) * 64 + q * 16 + (n & 15)) << 3) + j] = f_to_bf16(v);
        }
    } else {
        int i = (b - PREP_WF2) * 256 + tid;       // 392*256 = 100352
        if (i < 100352) ic[i] = 0;
    }
}

// ---------------------------------------------------------------------------
// Mean-gather, one 16-lane group per node (16 nodes/block, 4/wave).
// Measured memory-system-bound (~41 us); unchanged.
// ---------------------------------------------------------------------------
__global__ __launch_bounds__(256) void gather_mean_grp_kernel(
    const u32* __restrict__ feat,    // [N][64] u32 (=128 bf16)
    const int* __restrict__ cs, const int* __restrict__ pc, const int* __restrict__ ic,
    u32* __restrict__ A)             // [N][64] u32
{
    const int grp  = threadIdx.x >> 4;            // 0..15
    const int ch   = threadIdx.x & 15;            // 16B chunk within row
    const int node = blockIdx.x * 16 + grp;       // grid*16 == N exactly
    const int end  = pc[node];
    const int deg  = ic[node];
    const int start = end - deg;

    const u32* fb = feat + (ch << 2);             // lane's chunk base

    float acc[8] = {0.f,0.f,0.f,0.f,0.f,0.f,0.f,0.f};
    const uint4 Z = {0u, 0u, 0u, 0u};

    if (deg > 0) {
        uint4 c0 = *reinterpret_cast<const uint4*>(fb + ((size_t)cs[start] << 6));
        uint4 c1 = (deg > 1)
            ? *reinterpret_cast<const uint4*>(fb + ((size_t)cs[start + 1] << 6)) : Z;
        for (int j = 0; j < deg; ++j) {
            uint4 n = (j + 2 < deg)
                ? *reinterpret_cast<const uint4*>(fb + ((size_t)cs[start + j + 2] << 6)) : Z;
            acc[0] += bf16lo_to_f(c0.x); acc[1] += bf16hi_to_f(c0.x);
            acc[2] += bf16lo_to_f(c0.y); acc[3] += bf16hi_to_f(c0.y);
            acc[4] += bf16lo_to_f(c0.z); acc[5] += bf16hi_to_f(c0.z);
            acc[6] += bf16lo_to_f(c0.w); acc[7] += bf16hi_to_f(c0.w);
            c0 = c1; c1 = n;
        }
    }

    float inv = 1.0f / (float)(deg > 0 ? deg : 1);
    uint4 o;
    o.x = pack_bf16x2(acc[0] * inv, acc[1] * inv);
    o.y = pack_bf16x2(acc[2] * inv, acc[3] * inv);
    o.z = pack_bf16x2(acc[4] * inv, acc[5] * inv);
    o.w = pack_bf16x2(acc[6] * inv, acc[7] * inv);
    *reinterpret_cast<uint4*>(A + ((size_t)node << 6) + (ch << 2)) = o;
}

// Stage a packed W matrix linearly into LDS via global_load_lds (4-wave form,
// nchunk4*4 KB total; used by the 256-thread head kernel).
__device__ inline void stage_w(const u16* __restrict__ Wp, u16* __restrict__ sDst,
                               int wave, int lane, int nchunk4)
{
    for (int it = 0; it < nchunk4; ++it) {
        int off = (it * 4 + wave) << 9;             // 1 KB chunks
        __builtin_amdgcn_global_load_lds(
            (const __attribute__((address_space(1))) void*)(Wp + off + (lane << 3)),
            (__attribute__((address_space(3))) void*)(sDst + off), 16, 0, 0);
    }
}

// 8-wave form: stage one full 32 KB W matrix (32 x 1 KB chunks).
__device__ inline void stage_w8(const u16* __restrict__ Wp, u16* __restrict__ sDst,
                                int wave, int lane)
{
    #pragma unroll
    for (int it = 0; it < 4; ++it) {
        int off = (it * 8 + wave) << 9;             // 1 KB chunks, 32 total
        __builtin_amdgcn_global_load_lds(
            (const __attribute__((address_space(1))) void*)(Wp + off + (lane << 3)),
            (__attribute__((address_space(3))) void*)(sDst + off), 16, 0, 0);
    }
}

// ---------------------------------------------------------------------------
// MFMA dual GEMM v5: out = [relu]( A1 @ W1 + bias + A2 @ W2 )
// 512 threads, 8 waves, one 16-row tile per wave (128 rows/block).
// TRUE W double-buffer: W1 at sW[0..16K), W2 at sW[16K..32K) (64 KB LDS);
// a1/a2-frags + both W stages all issued before ONE vmcnt drain.
// 2 blocks/CU x 8 waves = 16 waves/CU (same residency as v3's 4x4).
// Epilogue reuses sW as [128][136] for coalesced uint4 bf16 stores; fp32
// (layer 3) stored direct.
// ---------------------------------------------------------------------------
__global__ __launch_bounds__(512) void mfma_gemm_kernel(
    const u16* __restrict__ A1, const u16* __restrict__ A2,
    const u16* __restrict__ W1p, const u16* __restrict__ W2p,
    const float* __restrict__ bias,
    u16* __restrict__ out16, float* __restrict__ out32, int do_relu)
{
    __shared__ __align__(16) u16 sW[32768];        // 64 KB: W1 | W2, then out staging
    const int tid  = threadIdx.x;
    const int wave = tid >> 6;                     // 0..7
    const int lane = tid & 63;
    const int m = lane & 15;
    const int q = lane >> 4;
    const int base = blockIdx.x * 128;

    int row = base + wave * 16 + m; if (row > N_NODES - 1) row = N_NODES - 1;

    // ---- phase 0: issue a1-frags + a2-frags + stage BOTH W mats, one drain ----
    bf16x8 a[4], c[4];
    #pragma unroll
    for (int ks = 0; ks < 4; ++ks) {
        a[ks] = *reinterpret_cast<const bf16x8*>(A1 + ((size_t)row << 7) + ((ks * 4 + q) << 3));
        c[ks] = *reinterpret_cast<const bf16x8*>(A2 + ((size_t)row << 7) + ((ks * 4 + q) << 3));
    }
    stage_w8(W1p, sW, wave, lane);
    stage_w8(W2p, sW + 16384, wave, lane);
    __syncthreads();   // single vmcnt drain

    f32x4 acc[8];
    #pragma unroll
    for (int nt = 0; nt < 8; ++nt) acc[nt] = (f32x4){0.f, 0.f, 0.f, 0.f};

    // ---- mat 1: aggr @ Wl ----
    #pragma unroll
    for (int ks = 0; ks < 4; ++ks) {
        #pragma unroll
        for (int nt = 0; nt < 8; ++nt) {
            bf16x8 b = *reinterpret_cast<const bf16x8*>(sW + (((nt * 4 + ks) * 64 + lane) << 3));
            acc[nt] = __builtin_amdgcn_mfma_f32_16x16x32_bf16(a[ks], b, acc[nt], 0, 0, 0);
        }
    }
    // ---- mat 2: self @ Wr ----
    #pragma unroll
    for (int ks = 0; ks < 4; ++ks) {
        #pragma unroll
        for (int nt = 0; nt < 8; ++nt) {
            bf16x8 b = *reinterpret_cast<const bf16x8*>(sW + 16384 + (((nt * 4 + ks) * 64 + lane) << 3));
            acc[nt] = __builtin_amdgcn_mfma_f32_16x16x32_bf16(c[ks], b, acc[nt], 0, 0, 0);
        }
    }
    __syncthreads();   // W frags dead; sW reusable for out staging

    // ---- fp32 direct stores (layer 3 only) ----
    if (out32) {
        #pragma unroll
        for (int nt = 0; nt < 8; ++nt) {
            int col = nt * 16 + m;
            float bv = bias[col];
            #pragma unroll
            for (int r = 0; r < 4; ++r) {
                int rg = base + wave * 16 + q * 4 + r;
                if (rg < N_NODES) out32[((size_t)rg << 7) + col] = acc[nt][r] + bv;
            }
        }
    }

    // ---- bf16 out through LDS [128][136] for coalesced uint4 stores ----
    if (out16) {
        #pragma unroll
        for (int nt = 0; nt < 8; ++nt) {
            int col = nt * 16 + m;
            float bv = bias[col];
            #pragma unroll
            for (int r = 0; r < 4; ++r) {
                float v = acc[nt][r] + bv;
                if (do_relu) v = fmaxf(v, 0.f);
                int rl = wave * 16 + q * 4 + r;
                sW[rl * 136 + col] = f_to_bf16(v);
            }
        }
        __syncthreads();
        #pragma unroll
        for (int it = 0; it < 4; ++it) {
            int cc = it * 512 + tid;               // 0..2047
            int rowl = cc >> 4, ch = cc & 15;
            int rowg = base + rowl;
            if (rowg < N_NODES)
                *reinterpret_cast<uint4*>(out16 + ((size_t)rowg << 7) + (ch << 3)) =
                    *reinterpret_cast<const uint4*>(sW + rowl * 136 + (ch << 3));
        }
    }
}

// ---------------------------------------------------------------------------
// Fused MLP head, 128 rows/block (proven in round 5): t = relu(h3 @ Wf1 +
// bf1) kept on-chip (two 64-row A-frag tiles in the dead Wf1 LDS buffer),
// then z = t @ Wf2 + bf2 and row-wise log_softmax in registers.
// ---------------------------------------------------------------------------
__global__ __launch_bounds__(256) void mfma_head_kernel(
    const u16* __restrict__ h3,      // bf16 [N][128]
    const u16* __restrict__ Wf1p, const float* __restrict__ bf1,
    const u16* __restrict__ Wf2p, const float* __restrict__ bf2,
    float* __restrict__ out)         // [N][40]
{
    __shared__ __align__(16) u16 sW1[16384];   // 32 KB: Wf1 frags -> t (2x64-row tiles)
    __shared__ __align__(16) u16 sW2[6144];    // 12 KB: Wf2 frags
    const int tid  = threadIdx.x;
    const int wave = tid >> 6;
    const int lane = tid & 63;
    const int m = lane & 15;
    const int q = lane >> 4;
    const int base = blockIdx.x * 128;

    int row0 = base + wave * 16 + m;       if (row0 > N_NODES - 1) row0 = N_NODES - 1;
    int row1 = base + 64 + wave * 16 + m;  if (row1 > N_NODES - 1) row1 = N_NODES - 1;

    bf16x8 a0[4], a1[4];
    #pragma unroll
    for (int ks = 0; ks < 4; ++ks) {
        a0[ks] = *reinterpret_cast<const bf16x8*>(h3 + ((size_t)row0 << 7) + ((ks * 4 + q) << 3));
        a1[ks] = *reinterpret_cast<const bf16x8*>(h3 + ((size_t)row1 << 7) + ((ks * 4 + q) << 3));
    }
    stage_w(Wf1p, sW1, wave, lane, 8);
    stage_w(Wf2p, sW2, wave, lane, 3);
    __syncthreads();

    // ---- GEMM1: acc = h3 @ Wf1 ----
    f32x4 acc0[8], acc1[8];
    #pragma unroll
    for (int nt = 0; nt < 8; ++nt) {
        acc0[nt] = (f32x4){0.f, 0.f, 0.f, 0.f};
        acc1[nt] = (f32x4){0.f, 0.f, 0.f, 0.f};
    }
    #pragma unroll
    for (int ks = 0; ks < 4; ++ks) {
        #pragma unroll
        for (int nt = 0; nt < 8; ++nt) {
            bf16x8 b = *reinterpret_cast<const bf16x8*>(sW1 + (((nt * 4 + ks) * 64 + lane) << 3));
            acc0[nt] = __builtin_amdgcn_mfma_f32_16x16x32_bf16(a0[ks], b, acc0[nt], 0, 0, 0);
            acc1[nt] = __builtin_amdgcn_mfma_f32_16x16x32_bf16(a1[ks], b, acc1[nt], 0, 0, 0);
        }
    }
    __syncthreads();   // Wf1 frags consumed; reuse sW1 for t

    // ---- t = relu(acc + bf1) -> sW1 (A-frag order; tile0 @0, tile1 @8192) ----
    #pragma unroll
    for (int nt = 0; nt < 8; ++nt) {
        int col = nt * 16 + m;
        float bv = bf1[col];
        #pragma unroll
        for (int r = 0; r < 4; ++r) {
            int dc = (wave * 4 + (nt >> 1)) * 64 + ((nt & 1) * 2 + (m >> 3)) * 16 + (q * 4 + r);
            sW1[(dc << 3) | (m & 7)]          = f_to_bf16(fmaxf(acc0[nt][r] + bv, 0.f));
            sW1[8192 + ((dc << 3) | (m & 7))] = f_to_bf16(fmaxf(acc1[nt][r] + bv, 0.f));
        }
    }
    __syncthreads();

    // ---- GEMM2: z = t @ Wf2 (48-padded cols) ----
    f32x4 ca[3], cb[3];
    #pragma unroll
    for (int nt = 0; nt < 3; ++nt) {
        ca[nt] = (f32x4){0.f, 0.f, 0.f, 0.f};
        cb[nt] = (f32x4){0.f, 0.f, 0.f, 0.f};
    }
    #pragma unroll
    for (int ks = 0; ks < 4; ++ks) {
        bf16x8 t0 = *reinterpret_cast<const bf16x8*>(sW1 + (((wave * 4 + ks) * 64 + lane) << 3));
        bf16x8 t1 = *reinterpret_cast<const bf16x8*>(sW1 + 8192 + (((wave * 4 + ks) * 64 + lane) << 3));
        #pragma unroll
        for (int nt = 0; nt < 3; ++nt) {
            bf16x8 b = *reinterpret_cast<const bf16x8*>(sW2 + (((nt * 4 + ks) * 64 + lane) << 3));
            ca[nt] = __builtin_amdgcn_mfma_f32_16x16x32_bf16(t0, b, ca[nt], 0, 0, 0);
            cb[nt] = __builtin_amdgcn_mfma_f32_16x16x32_bf16(t1, b, cb[nt], 0, 0, 0);
        }
    }

    // ---- log_softmax per 64-row tile, quad-local shuffle reductions ----
    #pragma unroll
    for (int tile = 0; tile < 2; ++tile) {
        const f32x4* acc2 = tile ? cb : ca;
        float z[3][4];
        float mx[4] = {-INFINITY, -INFINITY, -INFINITY, -INFINITY};
        #pragma unroll
        for (int nt = 0; nt < 3; ++nt) {
            int col = nt * 16 + m;
            bool valid = (col < ODIM);
            float bv = valid ? bf2[col] : 0.f;
            #pragma unroll
            for (int r = 0; r < 4; ++r) {
                z[nt][r] = acc2[nt][r] + bv;
                if (valid) mx[r] = fmaxf(mx[r], z[nt][r]);
            }
        }
        #pragma unroll
        for (int off = 1; off < 16; off <<= 1) {
            #pragma unroll
            for (int r = 0; r < 4; ++r) mx[r] = fmaxf(mx[r], __shfl_xor(mx[r], off, 16));
        }
        float sum[4] = {0.f, 0.f, 0.f, 0.f};
        #pragma unroll
        for (int nt = 0; nt < 3; ++nt) {
            int col = nt * 16 + m;
            if (col < ODIM) {
                #pragma unroll
                for (int r = 0; r < 4; ++r) sum[r] += expf(z[nt][r] - mx[r]);
            }
        }
        #pragma unroll
        for (int off = 1; off < 16; off <<= 1) {
            #pragma unroll
            for (int r = 0; r < 4; ++r) sum[r] += __shfl_xor(sum[r], off, 16);
        }
        float lse[4];
        #pragma unroll
        for (int r = 0; r < 4; ++r) lse[r] = logf(sum[r]) + mx[r];

        int rowbase = base + tile * 64 + wave * 16;
        #pragma unroll
        for (int nt = 0; nt < 3; ++nt) {
            int col = nt * 16 + m;
            if (col >= ODIM) continue;
            #pragma unroll
            for (int r = 0; r < 4; ++r) {
                int rowg = rowbase + q * 4 + r;
                if (rowg < N_NODES) out[(size_t)rowg * ODIM + col] = z[nt][r] - lse[r];
            }
        }
    }
}

// ---------------------------------------------------------------------------
extern "C" void kernel_launch(void* const* d_in, const int* in_sizes, int n_in,
                              void* d_out, int out_size, void* d_ws, size_t ws_size,
                              hipStream_t stream) {
    const float* x   = (const float*)d_in[0];
    const int*   ei  = (const int*)d_in[1];
    const int E = in_sizes[1] / 2;
    const int* src = ei;
    const int* dst = ei + E;

    const float* W1l = (const float*)d_in[2];
    const float* b1  = (const float*)d_in[3];
    const float* W1r = (const float*)d_in[4];
    const float* W2l = (const float*)d_in[5];
    const float* b2  = (const float*)d_in[6];
    const float* W2r = (const float*)d_in[7];
    const float* W3l = (const float*)d_in[8];
    const float* b3  = (const float*)d_in[9];
    const float* W3r = (const float*)d_in[10];
    const float* Wf1 = (const float*)d_in[11];
    const float* bf1 = (const float*)d_in[12];
    const float* Wf2 = (const float*)d_in[13];
    const float* bf2 = (const float*)d_in[14];

    float* out     = (float*)d_out;
    float* outTail = out + (size_t)N_NODES * ODIM;   // tuple part 2: h [N,128] fp32

    // CSR arrays live in d_out HEAD (overwritten by final softmax, which
    // launches after the last CSR use — head kernel reads no CSR).
    int* ic = (int*)out;            // 100352 ints
    int* pc = ic + 100352;          // 100352 ints
    int* bs = pc + 100352;          // 1024 ints
    int* cs = bs + 1024;            // E ints  (total ~3.4 MB < 16 MB head)

    // Workspace (u16 units): X16 | F16a | F16b | A16 | Wpk(7x16384) | Wf2p
    const size_t FEAT16 = (size_t)N_NODES * HDIM;   // 12.8M u16 = 25.6 MB
    u16* X16  = (u16*)d_ws;
    u16* F16a = X16  + FEAT16;
    u16* F16b = F16a + FEAT16;
    u16* A16  = F16b + FEAT16;
    u16* Wpk  = A16  + FEAT16;                      // 7*16384 u16
    u16* Wp_1l = Wpk + 0 * 16384;
    u16* Wp_1r = Wpk + 1 * 16384;
    u16* Wp_2l = Wpk + 2 * 16384;
    u16* Wp_2r = Wpk + 3 * 16384;
    u16* Wp_3l = Wpk + 4 * 16384;
    u16* Wp_3r = Wpk + 5 * 16384;
    u16* Wp_f1 = Wpk + 6 * 16384;
    u16* Wf2p  = Wpk + 7 * 16384;                   // 6144 u16

    const int gemmGrid   = (N_NODES + 127) / 128; // 782
    const int gatherGrid = N_NODES / 16;          // 6250 (16 nodes/block, exact)
    const int edgeGrid   = (E + 255) / 256;       // 2500

    // ---- fused prologue: f2bf + weight packs + ic zero (1 dispatch) ----
    WPtrs wp; wp.w[0] = W1l; wp.w[1] = W1r; wp.w[2] = W2l; wp.w[3] = W2r;
    wp.w[4] = W3l; wp.w[5] = W3r; wp.w[6] = Wf1;
    prep_kernel<<<PREP_ZERO, 256, 0, stream>>>(
        (const float2*)x, (u32*)X16, wp, Wpk, Wf2, Wf2p, ic);

    // ---- CSR build ----
    count_deg_kernel<<<edgeGrid, 256, 0, stream>>>(dst, ic, E);
    block_sum_kernel<<<NBLK, 256, 0, stream>>>(ic, bs, N_NODES);
    scan_bs_kernel<<<1, 512, 0, stream>>>(bs, NBLK);
    scan_block_kernel<<<NBLK, 256, 0, stream>>>(ic, bs, pc, N_NODES);
    fill_kernel<<<edgeGrid, 256, 0, stream>>>(src, dst, pc, cs, E);

    // ---- layer 1: X16 -> F16a ----
    gather_mean_grp_kernel<<<gatherGrid, 256, 0, stream>>>((const u32*)X16, cs, pc, ic, (u32*)A16);
    mfma_gemm_kernel<<<gemmGrid, 512, 0, stream>>>(A16, X16, Wp_1l, Wp_1r, b1, F16a, nullptr, 1);

    // ---- layer 2: F16a -> F16b ----
    gather_mean_grp_kernel<<<gatherGrid, 256, 0, stream>>>((const u32*)F16a, cs, pc, ic, (u32*)A16);
    mfma_gemm_kernel<<<gemmGrid, 512, 0, stream>>>(A16, F16a, Wp_2l, Wp_2r, b2, F16b, nullptr, 1);

    // ---- layer 3: F16b -> F16a (bf16) + outTail (fp32 h3), no relu ----
    gather_mean_grp_kernel<<<gatherGrid, 256, 0, stream>>>((const u32*)F16b, cs, pc, ic, (u32*)A16);
    mfma_gemm_kernel<<<gemmGrid, 512, 0, stream>>>(A16, F16b, Wp_3l, Wp_3r, b3, F16a, outTail, 0);

    // ---- fused MLP head + log_softmax -> out head (overwrites CSR debris) ----
    mfma_head_kernel<<<gemmGrid, 256, 0, stream>>>(F16a, Wp_f1, bf1, Wf2p, bf2, out);
}